// Round 2
// baseline (1271.524 us; speedup 1.0000x reference)
//
#include <hip/hip_runtime.h>
#include <math.h>

typedef __attribute__((ext_vector_type(8))) short short8;
typedef __attribute__((ext_vector_type(8))) unsigned short ushort8;
typedef __attribute__((ext_vector_type(4))) unsigned short ushort4v;
typedef __attribute__((ext_vector_type(4))) unsigned int uint4v;
typedef __attribute__((ext_vector_type(4))) float f32x4;

__device__ __forceinline__ unsigned short f2bf(float f) {
  union { float f; unsigned u; } v; v.f = f;
  unsigned u = v.u;
  return (unsigned short)((u + 0x7fffu + ((u >> 16) & 1u)) >> 16);
}

// ---------------------------------------------------------------------------
// Kernel 1: per-row gates g[l] = sigmoid(x[n,:] . w[l,:]), write xg = x*g (bf16)
// x: [4096, 3072] f32, w: [3, 3072] f32, xg: [4096, 3072] bf16
// ---------------------------------------------------------------------------
__global__ __launch_bounds__(256)
void gates_kernel(const float* __restrict__ x, const float* __restrict__ w,
                  unsigned short* __restrict__ xg) {
  const int n = blockIdx.x;
  const int t = threadIdx.x;
  const float* xr = x + (size_t)n * 3072;

  f32x4 xv[3];
#pragma unroll
  for (int c = 0; c < 3; ++c)
    xv[c] = *(const f32x4*)(xr + c * 1024 + t * 4);

  float p[3] = {0.f, 0.f, 0.f};
#pragma unroll
  for (int l = 0; l < 3; ++l) {
#pragma unroll
    for (int c = 0; c < 3; ++c) {
      f32x4 wv = *(const f32x4*)(w + l * 3072 + c * 1024 + t * 4);
      p[l] += xv[c][0] * wv[0] + xv[c][1] * wv[1] + xv[c][2] * wv[2] + xv[c][3] * wv[3];
    }
  }
  // wave butterfly reduce (64 lanes)
#pragma unroll
  for (int off = 32; off; off >>= 1) {
    p[0] += __shfl_xor(p[0], off);
    p[1] += __shfl_xor(p[1], off);
    p[2] += __shfl_xor(p[2], off);
  }
  __shared__ float sred[4][3];
  const int wave = t >> 6, lane = t & 63;
  if (lane == 0) {
    sred[wave][0] = p[0]; sred[wave][1] = p[1]; sred[wave][2] = p[2];
  }
  __syncthreads();
  float g[3];
#pragma unroll
  for (int l = 0; l < 3; ++l) {
    float s = sred[0][l] + sred[1][l] + sred[2][l] + sred[3][l];
    g[l] = 1.f / (1.f + expf(-s));
  }
  unsigned short* orow = xg + (size_t)n * 3072;
#pragma unroll
  for (int c = 0; c < 3; ++c) {
    ushort4v o;
#pragma unroll
    for (int j = 0; j < 4; ++j) o[j] = f2bf(xv[c][j] * g[c]);
    *(ushort4v*)(orow + c * 1024 + t * 4) = o;
  }
}

// ---------------------------------------------------------------------------
// Templated bf16 MFMA GEMM: C[4096, N] = A[4096, K](bf16) @ B[K, N](f32->bf16)
// EPI 0: relu(acc + sum_l emb_b[l][c])     -> bf16
// EPI 1: tanh(acc + bias[c])               -> bf16
// EPI 2: acc + bias[c]                     -> f32
// Tile 128x128x64, 256 threads (4 waves in 2x2), 4x4 16x16 frags per wave.
// ---------------------------------------------------------------------------
#define BM 128
#define BN 128
#define BK 64

template <int EPI>
__global__ __launch_bounds__(256)
void gemm_bf16(const unsigned short* __restrict__ A,
               const float* __restrict__ B,
               const float* __restrict__ bias,
               unsigned short* __restrict__ Cb,
               float* __restrict__ Cf,
               int K, int N) {
  __shared__ __align__(16) unsigned short As[BM * BK]; // swizzled [m][k]
  __shared__ __align__(16) unsigned short Bs[BN * BK]; // swizzled, transposed [n][k]

  const int tid = threadIdx.x;
  const int lane = tid & 63;
  const int wv = tid >> 6;
  const int wm = wv >> 1, wn = wv & 1;
  const int mt = blockIdx.x & 31;   // 4096/128 = 32 m-tiles, m fastest (n-outer)
  const int nt = blockIdx.x >> 5;
  const int m0 = mt * BM, n0 = nt * BN;

  f32x4 acc[4][4] = {};

  for (int kt = 0; kt < K; kt += BK) {
    __syncthreads();
    // --- stage A tile: 128x64 bf16, linear global, swizzled LDS ---
#pragma unroll
    for (int i = 0; i < 4; ++i) {
      int q = tid + 256 * i;       // 0..1023, 16B chunks
      int row = q >> 3;            // 0..127
      int kc = q & 7;              // which 16B chunk in the 128B row
      uint4v v = *(const uint4v*)((const char*)A +
                   ((size_t)(m0 + row) * K + kt) * 2 + kc * 16);
      *(uint4v*)((char*)As + row * 128 + ((kc * 16) ^ ((row & 7) << 4))) = v;
    }
    // --- stage B tile: 64x128 f32 -> transposed bf16 Bs[n][k] ---
#pragma unroll
    for (int gi = 0; gi < 4; ++gi) {
      int q = tid + 256 * gi;      // 0..1023
      int nn = q & 127;
      int k8 = q >> 7;             // 0..7 (8-k group)
      const float* src = B + (size_t)(kt + k8 * 8) * N + (n0 + nn);
      ushort8 tv;
#pragma unroll
      for (int j = 0; j < 8; ++j) tv[j] = f2bf(src[(size_t)j * N]);
      *(ushort8*)((char*)Bs + nn * 128 + ((k8 * 16) ^ ((nn & 7) << 4))) = tv;
    }
    __syncthreads();
    // --- compute: 2 k-chunks of 32, 16 MFMA each ---
#pragma unroll
    for (int kk = 0; kk < 2; ++kk) {
      short8 av[4], bv[4];
      const int kb = kk * 64 + (lane >> 4) * 16;
#pragma unroll
      for (int mi = 0; mi < 4; ++mi) {
        int row = wm * 64 + mi * 16 + (lane & 15);
        av[mi] = *(const short8*)((const char*)As + row * 128 + (kb ^ ((row & 7) << 4)));
      }
#pragma unroll
      for (int ni = 0; ni < 4; ++ni) {
        int row = wn * 64 + ni * 16 + (lane & 15);
        bv[ni] = *(const short8*)((const char*)Bs + row * 128 + (kb ^ ((row & 7) << 4)));
      }
#pragma unroll
      for (int mi = 0; mi < 4; ++mi)
#pragma unroll
        for (int ni = 0; ni < 4; ++ni)
          acc[mi][ni] = __builtin_amdgcn_mfma_f32_16x16x32_bf16(av[mi], bv[ni], acc[mi][ni], 0, 0, 0);
    }
  }

  // --- epilogue; C/D frag mapping: col = lane&15, row = (lane>>4)*4 + j ---
  const int lr = lane >> 4, lc = lane & 15;
#pragma unroll
  for (int ni = 0; ni < 4; ++ni) {
    int c = n0 + wn * 64 + ni * 16 + lc;
    float bb;
    if (EPI == 0) bb = bias[c] + bias[N + c] + bias[2 * N + c];
    else          bb = bias[c];
#pragma unroll
    for (int mi = 0; mi < 4; ++mi) {
      int r0 = m0 + wm * 64 + mi * 16 + lr * 4;
      f32x4 v = acc[mi][ni];
#pragma unroll
      for (int j = 0; j < 4; ++j) {
        float val = v[j] + bb;
        size_t idx = (size_t)(r0 + j) * N + c;
        if (EPI == 0) { val = val > 0.f ? val : 0.f; Cb[idx] = f2bf(val); }
        else if (EPI == 1) { Cb[idx] = f2bf(tanhf(val)); }
        else { Cf[idx] = val; }
      }
    }
  }
}

// ---------------------------------------------------------------------------
extern "C" void kernel_launch(void* const* d_in, const int* in_sizes, int n_in,
                              void* d_out, int out_size, void* d_ws, size_t ws_size,
                              hipStream_t stream) {
  const float* x     = (const float*)d_in[0];  // [4,1024,3072]
  const float* w     = (const float*)d_in[1];  // [3,3072]
  const float* emb_w = (const float*)d_in[2];  // [3,1024,2048] == [3072,2048]
  const float* emb_b = (const float*)d_in[3];  // [3,2048]
  const float* lin_w = (const float*)d_in[4];  // [2,2048,2048]
  const float* lin_b = (const float*)d_in[5];  // [2,2048]
  const float* out_w = (const float*)d_in[6];  // [2048,32000]
  const float* out_b = (const float*)d_in[7];  // [32000]
  float* out = (float*)d_out;                  // [4096,32000] f32

  // scratch: intermediates live inside d_out (500 MiB, fully overwritten by
  // the final GEMM); only h2 must survive the final GEMM -> d_ws.
  unsigned short* xg = (unsigned short*)d_out;                                 // 25.2 MB
  unsigned short* h0 = (unsigned short*)((char*)d_out + (((size_t)128) << 20)); // 16.8 MB
  unsigned short* h1 = (unsigned short*)((char*)d_out + (((size_t)160) << 20)); // 16.8 MB
  unsigned short* h2 = (unsigned short*)d_ws;                                  // 16.8 MB

  gates_kernel<<<4096, 256, 0, stream>>>(x, w, xg);
  // s = relu(xg @ emb_w + sum emb_b)
  gemm_bf16<0><<<32 * 16, 256, 0, stream>>>(xg, emb_w, emb_b, h0, nullptr, 3072, 2048);
  // h1 = tanh(h0 @ lin_w[0] + lin_b[0])
  gemm_bf16<1><<<32 * 16, 256, 0, stream>>>(h0, lin_w, lin_b, h1, nullptr, 2048, 2048);
  // h2 = tanh(h1 @ lin_w[1] + lin_b[1])
  gemm_bf16<1><<<32 * 16, 256, 0, stream>>>(h1, lin_w + 2048 * 2048, lin_b + 2048, h2, nullptr, 2048, 2048);
  // out = h2 @ out_w + out_b
  gemm_bf16<2><<<32 * 250, 256, 0, stream>>>(h2, out_w, out_b, nullptr, out, 2048, 32000);
}

// Round 3
// 1127.464 us; speedup vs baseline: 1.1278x; 1.1278x over previous
//
#include <hip/hip_runtime.h>
#include <math.h>

typedef __attribute__((ext_vector_type(8))) short short8;
typedef __attribute__((ext_vector_type(8))) unsigned short ushort8;
typedef __attribute__((ext_vector_type(4))) unsigned short ushort4v;
typedef __attribute__((ext_vector_type(4))) unsigned int uint4v;
typedef __attribute__((ext_vector_type(4))) float f32x4;

__device__ __forceinline__ unsigned short f2bf(float f) {
  union { float f; unsigned u; } v; v.f = f;
  unsigned u = v.u;
  return (unsigned short)((u + 0x7fffu + ((u >> 16) & 1u)) >> 16);
}

__device__ __forceinline__ void gload_lds16(const void* g, void* lds) {
  __builtin_amdgcn_global_load_lds(
      (const __attribute__((address_space(1))) unsigned int*)g,
      (__attribute__((address_space(3))) unsigned int*)lds, 16, 0, 0);
}

// ---------------------------------------------------------------------------
// Kernel 1: per-row gates g[l] = sigmoid(x[n,:] . w[l,:]), write xg = x*g (bf16)
// ---------------------------------------------------------------------------
__global__ __launch_bounds__(256)
void gates_kernel(const float* __restrict__ x, const float* __restrict__ w,
                  unsigned short* __restrict__ xg) {
  const int n = blockIdx.x;
  const int t = threadIdx.x;
  const float* xr = x + (size_t)n * 3072;

  f32x4 xv[3];
#pragma unroll
  for (int c = 0; c < 3; ++c)
    xv[c] = *(const f32x4*)(xr + c * 1024 + t * 4);

  float p[3] = {0.f, 0.f, 0.f};
#pragma unroll
  for (int l = 0; l < 3; ++l) {
#pragma unroll
    for (int c = 0; c < 3; ++c) {
      f32x4 wv = *(const f32x4*)(w + l * 3072 + c * 1024 + t * 4);
      p[l] += xv[c][0] * wv[0] + xv[c][1] * wv[1] + xv[c][2] * wv[2] + xv[c][3] * wv[3];
    }
  }
#pragma unroll
  for (int off = 32; off; off >>= 1) {
    p[0] += __shfl_xor(p[0], off);
    p[1] += __shfl_xor(p[1], off);
    p[2] += __shfl_xor(p[2], off);
  }
  __shared__ float sred[4][3];
  const int wave = t >> 6, lane = t & 63;
  if (lane == 0) {
    sred[wave][0] = p[0]; sred[wave][1] = p[1]; sred[wave][2] = p[2];
  }
  __syncthreads();
  float g[3];
#pragma unroll
  for (int l = 0; l < 3; ++l) {
    float s = sred[0][l] + sred[1][l] + sred[2][l] + sred[3][l];
    g[l] = 1.f / (1.f + expf(-s));
  }
  unsigned short* orow = xg + (size_t)n * 3072;
#pragma unroll
  for (int c = 0; c < 3; ++c) {
    ushort4v o;
#pragma unroll
    for (int j = 0; j < 4; ++j) o[j] = f2bf(xv[c][j] * g[c]);
    *(ushort4v*)(orow + c * 1024 + t * 4) = o;
  }
}

// ---------------------------------------------------------------------------
// Transpose + convert: in f32 [R][C] row-major -> out bf16 [C][R] row-major.
// 64x64 tiles via LDS; grid = (C/64, R/64), block 256.
// ---------------------------------------------------------------------------
__global__ __launch_bounds__(256)
void transcvt_kernel(const float* __restrict__ in, unsigned short* __restrict__ outp,
                     int R, int C) {
  __shared__ float tile[64][65];
  const int c0 = blockIdx.x * 64, r0 = blockIdx.y * 64;
  const int t = threadIdx.x;
  const int tr = t >> 4;           // 0..15
  const int tc = (t & 15) * 4;     // 0..60
#pragma unroll
  for (int p = 0; p < 4; ++p) {
    int r = p * 16 + tr;
    f32x4 v = *(const f32x4*)(in + (size_t)(r0 + r) * C + c0 + tc);
    tile[r][tc] = v[0]; tile[r][tc + 1] = v[1];
    tile[r][tc + 2] = v[2]; tile[r][tc + 3] = v[3];
  }
  __syncthreads();
  const int c = t >> 2;            // output row within tile (0..63)
  const int rb = (t & 3) * 16;     // 16 source rows per thread
  ushort8 o0, o1;
#pragma unroll
  for (int j = 0; j < 8; ++j) o0[j] = f2bf(tile[rb + j][c]);
#pragma unroll
  for (int j = 0; j < 8; ++j) o1[j] = f2bf(tile[rb + 8 + j][c]);
  unsigned short* dst = outp + (size_t)(c0 + c) * R + r0 + rb;
  *(ushort8*)dst = o0;
  *(ushort8*)(dst + 8) = o1;
}

// ---------------------------------------------------------------------------
// Fast GEMM: C[4096, N] = A[M][K](bf16) @ Bt[N][K](bf16)^T
// m97 structure: global_load_lds staging (linear LDS dest, pre-swizzled global
// source), XOR-swizzled ds_read_b128 fragment reads.
// Tile 128x128x64, 256 threads (2x2 waves), 4x4 16x16x32 frags per wave.
// EPI 0: relu(acc + emb_b summed)  -> bf16
// EPI 1: tanh(acc + bias)          -> bf16
// EPI 2: acc + bias                -> f32
// ---------------------------------------------------------------------------
template <int EPI>
__global__ __launch_bounds__(256)
void gemm_tt(const unsigned short* __restrict__ A,
             const unsigned short* __restrict__ Bt,
             const float* __restrict__ bias,
             unsigned short* __restrict__ Cb,
             float* __restrict__ Cf,
             int K, int N) {
  __shared__ __align__(16) unsigned short As[128 * 64];
  __shared__ __align__(16) unsigned short Bs[128 * 64];

  const int tid = threadIdx.x;
  const int lane = tid & 63;
  const int wv = tid >> 6;
  const int wm = wv >> 1, wn = wv & 1;
  const int mt = blockIdx.x & 31;   // m fastest: 32 blocks share one B panel
  const int nt = blockIdx.x >> 5;
  const int m0 = mt * 128, n0 = nt * 128;
  const size_t strideB = (size_t)K * 2;   // row bytes

  f32x4 acc[4][4] = {};

  for (int kt = 0; kt < K; kt += 64) {
    __syncthreads();
    // stage: each wave issues 4 x 1KB loads per buffer; LDS dest is
    // wave-uniform base (+ lane*16 by HW); global source pre-swizzled.
#pragma unroll
    for (int i = 0; i < 4; ++i) {
      const int o = wv * 4096 + i * 1024 + lane * 16;  // this lane's dest byte
      const int row = o >> 7;                          // 128B rows
      const int sw = (((o >> 4) & 7) * 16) ^ ((row & 7) << 4);
      gload_lds16((const char*)A + (size_t)(m0 + row) * strideB + (size_t)kt * 2 + sw,
                  (char*)As + wv * 4096 + i * 1024);
      gload_lds16((const char*)Bt + (size_t)(n0 + row) * strideB + (size_t)kt * 2 + sw,
                  (char*)Bs + wv * 4096 + i * 1024);
    }
    __syncthreads();  // compiler drains vmcnt before s_barrier
#pragma unroll
    for (int kk = 0; kk < 2; ++kk) {
      short8 av[4], bv[4];
      const int kb = kk * 64 + (lane >> 4) * 16;       // byte offset in row
#pragma unroll
      for (int mi = 0; mi < 4; ++mi) {
        int row = wm * 64 + mi * 16 + (lane & 15);
        av[mi] = *(const short8*)((const char*)As + row * 128 + (kb ^ ((row & 7) << 4)));
      }
#pragma unroll
      for (int ni = 0; ni < 4; ++ni) {
        int row = wn * 64 + ni * 16 + (lane & 15);
        bv[ni] = *(const short8*)((const char*)Bs + row * 128 + (kb ^ ((row & 7) << 4)));
      }
#pragma unroll
      for (int mi = 0; mi < 4; ++mi)
#pragma unroll
        for (int ni = 0; ni < 4; ++ni)
          acc[mi][ni] = __builtin_amdgcn_mfma_f32_16x16x32_bf16(av[mi], bv[ni], acc[mi][ni], 0, 0, 0);
    }
  }

  // epilogue; C/D frag mapping: col = lane&15, row = (lane>>4)*4 + j
  const int lr = lane >> 4, lc = lane & 15;
#pragma unroll
  for (int ni = 0; ni < 4; ++ni) {
    int c = n0 + wn * 64 + ni * 16 + lc;
    float bb;
    if (EPI == 0) bb = bias[c] + bias[N + c] + bias[2 * N + c];
    else          bb = bias[c];
#pragma unroll
    for (int mi = 0; mi < 4; ++mi) {
      int r0 = m0 + wm * 64 + mi * 16 + lr * 4;
      f32x4 v = acc[mi][ni];
#pragma unroll
      for (int j = 0; j < 4; ++j) {
        float val = v[j] + bb;
        size_t idx = (size_t)(r0 + j) * N + c;
        if (EPI == 0) { val = val > 0.f ? val : 0.f; Cb[idx] = f2bf(val); }
        else if (EPI == 1) { Cb[idx] = f2bf(tanhf(val)); }
        else { Cf[idx] = val; }
      }
    }
  }
}

// ---------------------------------------------------------------------------
// Fallback GEMM (round-2 proven): B is f32 [K][N], converted during staging.
// Only used for the final GEMM if ws_size is too small for out_wT.
// ---------------------------------------------------------------------------
template <int EPI>
__global__ __launch_bounds__(256)
void gemm_bf16(const unsigned short* __restrict__ A,
               const float* __restrict__ B,
               const float* __restrict__ bias,
               unsigned short* __restrict__ Cb,
               float* __restrict__ Cf,
               int K, int N) {
  __shared__ __align__(16) unsigned short As[128 * 64];
  __shared__ __align__(16) unsigned short Bs[128 * 64];

  const int tid = threadIdx.x;
  const int lane = tid & 63;
  const int wv = tid >> 6;
  const int wm = wv >> 1, wn = wv & 1;
  const int mt = blockIdx.x & 31;
  const int nt = blockIdx.x >> 5;
  const int m0 = mt * 128, n0 = nt * 128;

  f32x4 acc[4][4] = {};

  for (int kt = 0; kt < K; kt += 64) {
    __syncthreads();
#pragma unroll
    for (int i = 0; i < 4; ++i) {
      int q = tid + 256 * i;
      int row = q >> 3;
      int kc = q & 7;
      uint4v v = *(const uint4v*)((const char*)A +
                   ((size_t)(m0 + row) * K + kt) * 2 + kc * 16);
      *(uint4v*)((char*)As + row * 128 + ((kc * 16) ^ ((row & 7) << 4))) = v;
    }
#pragma unroll
    for (int gi = 0; gi < 4; ++gi) {
      int q = tid + 256 * gi;
      int nn = q & 127;
      int k8 = q >> 7;
      const float* src = B + (size_t)(kt + k8 * 8) * N + (n0 + nn);
      ushort8 tv;
#pragma unroll
      for (int j = 0; j < 8; ++j) tv[j] = f2bf(src[(size_t)j * N]);
      *(ushort8*)((char*)Bs + nn * 128 + ((k8 * 16) ^ ((nn & 7) << 4))) = tv;
    }
    __syncthreads();
#pragma unroll
    for (int kk = 0; kk < 2; ++kk) {
      short8 av[4], bv[4];
      const int kb = kk * 64 + (lane >> 4) * 16;
#pragma unroll
      for (int mi = 0; mi < 4; ++mi) {
        int row = wm * 64 + mi * 16 + (lane & 15);
        av[mi] = *(const short8*)((const char*)As + row * 128 + (kb ^ ((row & 7) << 4)));
      }
#pragma unroll
      for (int ni = 0; ni < 4; ++ni) {
        int row = wn * 64 + ni * 16 + (lane & 15);
        bv[ni] = *(const short8*)((const char*)Bs + row * 128 + (kb ^ ((row & 7) << 4)));
      }
#pragma unroll
      for (int mi = 0; mi < 4; ++mi)
#pragma unroll
        for (int ni = 0; ni < 4; ++ni)
          acc[mi][ni] = __builtin_amdgcn_mfma_f32_16x16x32_bf16(av[mi], bv[ni], acc[mi][ni], 0, 0, 0);
    }
  }

  const int lr = lane >> 4, lc = lane & 15;
#pragma unroll
  for (int ni = 0; ni < 4; ++ni) {
    int c = n0 + wn * 64 + ni * 16 + lc;
    float bb = bias[c];
#pragma unroll
    for (int mi = 0; mi < 4; ++mi) {
      int r0 = m0 + wm * 64 + mi * 16 + lr * 4;
      f32x4 v = acc[mi][ni];
#pragma unroll
      for (int j = 0; j < 4; ++j) {
        float val = v[j] + bb;
        size_t idx = (size_t)(r0 + j) * N + c;
        if (EPI == 1) { Cb[idx] = f2bf(tanhf(val)); }
        else { Cf[idx] = val; }
      }
    }
  }
}

// ---------------------------------------------------------------------------
extern "C" void kernel_launch(void* const* d_in, const int* in_sizes, int n_in,
                              void* d_out, int out_size, void* d_ws, size_t ws_size,
                              hipStream_t stream) {
  const float* x     = (const float*)d_in[0];  // [4,1024,3072]
  const float* w     = (const float*)d_in[1];  // [3,3072]
  const float* emb_w = (const float*)d_in[2];  // [3072,2048]
  const float* emb_b = (const float*)d_in[3];  // [3,2048]
  const float* lin_w = (const float*)d_in[4];  // [2,2048,2048]
  const float* lin_b = (const float*)d_in[5];  // [2,2048]
  const float* out_w = (const float*)d_in[6];  // [2048,32000]
  const float* out_b = (const float*)d_in[7];  // [32000]
  float* out = (float*)d_out;                  // [4096,32000] f32

  // d_out scratch layout (all dead before the final GEMM overwrites d_out):
  char* ob = (char*)d_out;
  unsigned short* xg      = (unsigned short*)ob;                              // 25.2 MB
  unsigned short* h0      = (unsigned short*)(ob + (((size_t)128) << 20));    // 16.8 MB
  unsigned short* h1      = (unsigned short*)(ob + (((size_t)160) << 20));    // 16.8 MB
  unsigned short* emb_wT  = (unsigned short*)(ob + (((size_t)192) << 20));    // 12.6 MB
  unsigned short* lin_wT0 = (unsigned short*)(ob + (((size_t)208) << 20));    //  8.4 MB
  unsigned short* lin_wT1 = (unsigned short*)(ob + (((size_t)224) << 20));    //  8.4 MB
  // d_ws: h2 must survive the final GEMM; out_wT must too (if it fits).
  unsigned short* h2      = (unsigned short*)d_ws;                            // 16.8 MB
  unsigned short* out_wT  = (unsigned short*)((char*)d_ws + (((size_t)32) << 20)); // 131 MB
  const bool fast4 = ws_size >= ((((size_t)32) << 20) + (size_t)32000 * 2048 * 2);

  gates_kernel<<<4096, 256, 0, stream>>>(x, w, xg);
  transcvt_kernel<<<dim3(32, 48), 256, 0, stream>>>(emb_w, emb_wT, 3072, 2048);
  transcvt_kernel<<<dim3(32, 32), 256, 0, stream>>>(lin_w, lin_wT0, 2048, 2048);
  transcvt_kernel<<<dim3(32, 32), 256, 0, stream>>>(lin_w + 2048 * 2048, lin_wT1, 2048, 2048);
  if (fast4)
    transcvt_kernel<<<dim3(500, 32), 256, 0, stream>>>(out_w, out_wT, 2048, 32000);

  // s = relu(xg @ emb_w + sum emb_b)
  gemm_tt<0><<<32 * 16, 256, 0, stream>>>(xg, emb_wT, emb_b, h0, nullptr, 3072, 2048);
  // h1 = tanh(h0 @ lin_w[0] + lin_b[0])
  gemm_tt<1><<<32 * 16, 256, 0, stream>>>(h0, lin_wT0, lin_b, h1, nullptr, 2048, 2048);
  // h2 = tanh(h1 @ lin_w[1] + lin_b[1])
  gemm_tt<1><<<32 * 16, 256, 0, stream>>>(h1, lin_wT1, lin_b + 2048, h2, nullptr, 2048, 2048);
  // out = h2 @ out_w + out_b
  if (fast4)
    gemm_tt<2><<<32 * 250, 256, 0, stream>>>(h2, out_wT, out_b, nullptr, out, 2048, 32000);
  else
    gemm_bf16<2><<<32 * 250, 256, 0, stream>>>(h2, out_w, out_b, nullptr, out, 2048, 32000);
}

// Round 4
// 956.750 us; speedup vs baseline: 1.3290x; 1.1784x over previous
//
#include <hip/hip_runtime.h>
#include <math.h>

typedef __attribute__((ext_vector_type(8))) short short8;
typedef __attribute__((ext_vector_type(8))) unsigned short ushort8;
typedef __attribute__((ext_vector_type(4))) unsigned short ushort4v;
typedef __attribute__((ext_vector_type(4))) unsigned int uint4v;
typedef __attribute__((ext_vector_type(4))) float f32x4;

__device__ __forceinline__ unsigned short f2bf(float f) {
  union { float f; unsigned u; } v; v.f = f;
  unsigned u = v.u;
  return (unsigned short)((u + 0x7fffu + ((u >> 16) & 1u)) >> 16);
}

__device__ __forceinline__ void gload_lds16(const void* g, void* lds) {
  __builtin_amdgcn_global_load_lds(
      (const __attribute__((address_space(1))) unsigned int*)g,
      (__attribute__((address_space(3))) unsigned int*)lds, 16, 0, 0);
}

// ---------------------------------------------------------------------------
// Kernel 1: per-row gates g[l] = sigmoid(x[n,:] . w[l,:]), write xg = x*g (bf16)
// ---------------------------------------------------------------------------
__global__ __launch_bounds__(256)
void gates_kernel(const float* __restrict__ x, const float* __restrict__ w,
                  unsigned short* __restrict__ xg) {
  const int n = blockIdx.x;
  const int t = threadIdx.x;
  const float* xr = x + (size_t)n * 3072;

  f32x4 xv[3];
#pragma unroll
  for (int c = 0; c < 3; ++c)
    xv[c] = *(const f32x4*)(xr + c * 1024 + t * 4);

  float p[3] = {0.f, 0.f, 0.f};
#pragma unroll
  for (int l = 0; l < 3; ++l) {
#pragma unroll
    for (int c = 0; c < 3; ++c) {
      f32x4 wv = *(const f32x4*)(w + l * 3072 + c * 1024 + t * 4);
      p[l] += xv[c][0] * wv[0] + xv[c][1] * wv[1] + xv[c][2] * wv[2] + xv[c][3] * wv[3];
    }
  }
#pragma unroll
  for (int off = 32; off; off >>= 1) {
    p[0] += __shfl_xor(p[0], off);
    p[1] += __shfl_xor(p[1], off);
    p[2] += __shfl_xor(p[2], off);
  }
  __shared__ float sred[4][3];
  const int wave = t >> 6, lane = t & 63;
  if (lane == 0) {
    sred[wave][0] = p[0]; sred[wave][1] = p[1]; sred[wave][2] = p[2];
  }
  __syncthreads();
  float g[3];
#pragma unroll
  for (int l = 0; l < 3; ++l) {
    float s = sred[0][l] + sred[1][l] + sred[2][l] + sred[3][l];
    g[l] = 1.f / (1.f + expf(-s));
  }
  unsigned short* orow = xg + (size_t)n * 3072;
#pragma unroll
  for (int c = 0; c < 3; ++c) {
    ushort4v o;
#pragma unroll
    for (int j = 0; j < 4; ++j) o[j] = f2bf(xv[c][j] * g[c]);
    *(ushort4v*)(orow + c * 1024 + t * 4) = o;
  }
}

// ---------------------------------------------------------------------------
// Transpose + convert: in f32 [R][C] row-major -> out bf16 [C][R] row-major.
// ---------------------------------------------------------------------------
__global__ __launch_bounds__(256)
void transcvt_kernel(const float* __restrict__ in, unsigned short* __restrict__ outp,
                     int R, int C) {
  __shared__ float tile[64][65];
  const int c0 = blockIdx.x * 64, r0 = blockIdx.y * 64;
  const int t = threadIdx.x;
  const int tr = t >> 4;
  const int tc = (t & 15) * 4;
#pragma unroll
  for (int p = 0; p < 4; ++p) {
    int r = p * 16 + tr;
    f32x4 v = *(const f32x4*)(in + (size_t)(r0 + r) * C + c0 + tc);
    tile[r][tc] = v[0]; tile[r][tc + 1] = v[1];
    tile[r][tc + 2] = v[2]; tile[r][tc + 3] = v[3];
  }
  __syncthreads();
  const int c = t >> 2;
  const int rb = (t & 3) * 16;
  ushort8 o0, o1;
#pragma unroll
  for (int j = 0; j < 8; ++j) o0[j] = f2bf(tile[rb + j][c]);
#pragma unroll
  for (int j = 0; j < 8; ++j) o1[j] = f2bf(tile[rb + 8 + j][c]);
  unsigned short* dst = outp + (size_t)(c0 + c) * R + r0 + rb;
  *(ushort8*)dst = o0;
  *(ushort8*)(dst + 8) = o1;
}

// ---------------------------------------------------------------------------
// Mid GEMM (proven, m97-structure): C[4096, N] = A(bf16) @ Bt(bf16)^T
// ---------------------------------------------------------------------------
template <int EPI>
__global__ __launch_bounds__(256)
void gemm_tt(const unsigned short* __restrict__ A,
             const unsigned short* __restrict__ Bt,
             const float* __restrict__ bias,
             unsigned short* __restrict__ Cb,
             float* __restrict__ Cf,
             int K, int N) {
  __shared__ __align__(16) unsigned short As[128 * 64];
  __shared__ __align__(16) unsigned short Bs[128 * 64];

  const int tid = threadIdx.x;
  const int lane = tid & 63;
  const int wv = tid >> 6;
  const int wm = wv >> 1, wn = wv & 1;
  const int mt = blockIdx.x & 31;
  const int nt = blockIdx.x >> 5;
  const int m0 = mt * 128, n0 = nt * 128;
  const size_t strideB = (size_t)K * 2;

  f32x4 acc[4][4] = {};

  for (int kt = 0; kt < K; kt += 64) {
    __syncthreads();
#pragma unroll
    for (int i = 0; i < 4; ++i) {
      const int o = wv * 4096 + i * 1024 + lane * 16;
      const int row = o >> 7;
      const int sw = (((o >> 4) & 7) * 16) ^ ((row & 7) << 4);
      gload_lds16((const char*)A + (size_t)(m0 + row) * strideB + (size_t)kt * 2 + sw,
                  (char*)As + wv * 4096 + i * 1024);
      gload_lds16((const char*)Bt + (size_t)(n0 + row) * strideB + (size_t)kt * 2 + sw,
                  (char*)Bs + wv * 4096 + i * 1024);
    }
    __syncthreads();
#pragma unroll
    for (int kk = 0; kk < 2; ++kk) {
      short8 av[4], bv[4];
      const int kb = kk * 64 + (lane >> 4) * 16;
#pragma unroll
      for (int mi = 0; mi < 4; ++mi) {
        int row = wm * 64 + mi * 16 + (lane & 15);
        av[mi] = *(const short8*)((const char*)As + row * 128 + (kb ^ ((row & 7) << 4)));
      }
#pragma unroll
      for (int ni = 0; ni < 4; ++ni) {
        int row = wn * 64 + ni * 16 + (lane & 15);
        bv[ni] = *(const short8*)((const char*)Bs + row * 128 + (kb ^ ((row & 7) << 4)));
      }
#pragma unroll
      for (int mi = 0; mi < 4; ++mi)
#pragma unroll
        for (int ni = 0; ni < 4; ++ni)
          acc[mi][ni] = __builtin_amdgcn_mfma_f32_16x16x32_bf16(av[mi], bv[ni], acc[mi][ni], 0, 0, 0);
    }
  }

  const int lr = lane >> 4, lc = lane & 15;
#pragma unroll
  for (int ni = 0; ni < 4; ++ni) {
    int c = n0 + wn * 64 + ni * 16 + lc;
    float bb;
    if (EPI == 0) bb = bias[c] + bias[N + c] + bias[2 * N + c];
    else          bb = bias[c];
#pragma unroll
    for (int mi = 0; mi < 4; ++mi) {
      int r0 = m0 + wm * 64 + mi * 16 + lr * 4;
      f32x4 v = acc[mi][ni];
#pragma unroll
      for (int j = 0; j < 4; ++j) {
        float val = v[j] + bb;
        size_t idx = (size_t)(r0 + j) * N + c;
        if (EPI == 0) { val = val > 0.f ? val : 0.f; Cb[idx] = f2bf(val); }
        else if (EPI == 1) { Cb[idx] = f2bf(tanhf(val)); }
        else { Cf[idx] = val; }
      }
    }
  }
}

// ---------------------------------------------------------------------------
// Final GEMM: 256x256x64 tile, 8 waves, double-buffered LDS, counted vmcnt
// (T3+T4), setprio MFMA clusters (T5), XCD swizzle (T1). M fixed = 4096.
// out[4096][N] = A[4096][K](bf16) @ Bt[N][K](bf16)^T + bias (f32 out)
// ---------------------------------------------------------------------------
__global__ __launch_bounds__(512, 2)
void gemm8_out(const unsigned short* __restrict__ A,
               const unsigned short* __restrict__ Bt,
               const float* __restrict__ bias,
               float* __restrict__ Cf,
               int K, int N) {
  __shared__ __align__(16) unsigned short As8[2][256 * 64];  // 64 KiB
  __shared__ __align__(16) unsigned short Bs8[2][256 * 64];  // 64 KiB

  const int tid = threadIdx.x;
  const int lane = tid & 63;
  const int wid = tid >> 6;
  const int wm = wid >> 2, wn = wid & 3;

  const int bid = blockIdx.x;
  const int cpx = gridDim.x >> 3;                 // grid % 8 == 0
  const int lid = (bid & 7) * cpx + (bid >> 3);   // T1 XCD swizzle
  const int mt = lid & 15;                        // 16 m-tiles (M = 4096)
  const int ntile = lid >> 4;
  const int m0 = mt * 256, n0 = ntile * 256;
  const size_t strideB = (size_t)K * 2;
  const int kTiles = K >> 6;

  // staging role: waves 0-3 stage A quarters, 4-7 stage B quarters
  const unsigned short* smat = (wid < 4) ? A : Bt;
  char* sb = (wid < 4) ? (char*)As8 : (char*)Bs8;
  const int part = wid & 3;
  const int srow0 = ((wid < 4) ? m0 : n0) + part * 64 + (lane >> 3);
  const int ssw = ((lane & 7) ^ (lane >> 3)) << 4;   // pre-swizzled source col

  auto stage8 = [&](int buf, int t) {
#pragma unroll
    for (int i = 0; i < 8; ++i)
      gload_lds16((const char*)smat + (size_t)(srow0 + i * 8) * strideB +
                      (size_t)t * 128 + ssw,
                  sb + buf * 32768 + part * 8192 + i * 1024);
  };

  // fragment-read constants
  const int l15 = lane & 15;
  const int kch = (lane >> 4) * 16;
  const int swr = (l15 & 7) << 4;

  f32x4 acc[8][4] = {};

  stage8(0, 0);
  stage8(1, 1);
  asm volatile("s_waitcnt vmcnt(8)" ::: "memory");   // tile 0 landed
  __builtin_amdgcn_sched_barrier(0);
  __builtin_amdgcn_s_barrier();

  for (int t = 0; t < kTiles; ++t) {
    const char* ab = (const char*)As8 + (t & 1) * 32768;
    const char* bb = (const char*)Bs8 + (t & 1) * 32768;
    short8 av[4][2], bva[2][2], bvb[2][2];

    // ---- phase 1: read A(mq0) + B(nq0), compute quad (0,0) ----
#pragma unroll
    for (int mi = 0; mi < 4; ++mi)
#pragma unroll
      for (int ks = 0; ks < 2; ++ks) {
        int r = wm * 128 + mi * 16 + l15;
        av[mi][ks] = *(const short8*)(ab + r * 128 + ((ks * 64 + kch) ^ swr));
      }
#pragma unroll
    for (int ni = 0; ni < 2; ++ni)
#pragma unroll
      for (int ks = 0; ks < 2; ++ks) {
        int r = wn * 64 + ni * 16 + l15;
        bva[ni][ks] = *(const short8*)(bb + r * 128 + ((ks * 64 + kch) ^ swr));
      }
    __builtin_amdgcn_s_setprio(1);
#pragma unroll
    for (int ks = 0; ks < 2; ++ks)
#pragma unroll
      for (int mi = 0; mi < 4; ++mi)
#pragma unroll
        for (int ni = 0; ni < 2; ++ni)
          acc[mi][ni] = __builtin_amdgcn_mfma_f32_16x16x32_bf16(
              av[mi][ks], bva[ni][ks], acc[mi][ni], 0, 0, 0);
    __builtin_amdgcn_s_setprio(0);

    // ---- phase 2: read B(nq1), compute quad (0,1) ----
#pragma unroll
    for (int ni = 0; ni < 2; ++ni)
#pragma unroll
      for (int ks = 0; ks < 2; ++ks) {
        int r = wn * 64 + 32 + ni * 16 + l15;
        bvb[ni][ks] = *(const short8*)(bb + r * 128 + ((ks * 64 + kch) ^ swr));
      }
    __builtin_amdgcn_s_setprio(1);
#pragma unroll
    for (int ks = 0; ks < 2; ++ks)
#pragma unroll
      for (int mi = 0; mi < 4; ++mi)
#pragma unroll
        for (int ni = 0; ni < 2; ++ni)
          acc[mi][2 + ni] = __builtin_amdgcn_mfma_f32_16x16x32_bf16(
              av[mi][ks], bvb[ni][ks], acc[mi][2 + ni], 0, 0, 0);
    __builtin_amdgcn_s_setprio(0);

    // ---- phase 3: read A(mq1), compute quad (1,1) ----
#pragma unroll
    for (int mi = 0; mi < 4; ++mi)
#pragma unroll
      for (int ks = 0; ks < 2; ++ks) {
        int r = wm * 128 + 64 + mi * 16 + l15;
        av[mi][ks] = *(const short8*)(ab + r * 128 + ((ks * 64 + kch) ^ swr));
      }
    __builtin_amdgcn_s_setprio(1);
#pragma unroll
    for (int ks = 0; ks < 2; ++ks)
#pragma unroll
      for (int mi = 0; mi < 4; ++mi)
#pragma unroll
        for (int ni = 0; ni < 2; ++ni)
          acc[4 + mi][2 + ni] = __builtin_amdgcn_mfma_f32_16x16x32_bf16(
              av[mi][ks], bvb[ni][ks], acc[4 + mi][2 + ni], 0, 0, 0);
    __builtin_amdgcn_s_setprio(0);

    // ---- phase 4: reuse B(nq0), compute quad (1,0) ----
    __builtin_amdgcn_s_setprio(1);
#pragma unroll
    for (int ks = 0; ks < 2; ++ks)
#pragma unroll
      for (int mi = 0; mi < 4; ++mi)
#pragma unroll
        for (int ni = 0; ni < 2; ++ni)
          acc[4 + mi][ni] = __builtin_amdgcn_mfma_f32_16x16x32_bf16(
              av[mi][ks], bva[ni][ks], acc[4 + mi][ni], 0, 0, 0);
    __builtin_amdgcn_s_setprio(0);

    // ---- trailer: counted-vmcnt double-buffer rotation ----
    if (t + 1 < kTiles) {
      __builtin_amdgcn_sched_barrier(0);
      __builtin_amdgcn_s_barrier();          // all waves done reading buf[t&1]
      if (t + 2 < kTiles) {
        stage8(t & 1, t + 2);                // overwrite just-read buffer
        asm volatile("s_waitcnt vmcnt(8)" ::: "memory");  // tile t+1 landed
      } else {
        asm volatile("s_waitcnt vmcnt(0)" ::: "memory");
      }
      __builtin_amdgcn_sched_barrier(0);
      __builtin_amdgcn_s_barrier();          // tile t+1 visible to all waves
    }
  }

  // ---- epilogue: C frag mapping col = lane&15, row = (lane>>4)*4 + j ----
  const int lr = lane >> 4;
#pragma unroll
  for (int ni = 0; ni < 4; ++ni) {
    int c = n0 + wn * 64 + ni * 16 + l15;
    float bb2 = bias[c];
#pragma unroll
    for (int mi = 0; mi < 8; ++mi) {
      int r0 = m0 + wm * 128 + mi * 16 + lr * 4;
#pragma unroll
      for (int j = 0; j < 4; ++j)
        Cf[(size_t)(r0 + j) * N + c] = acc[mi][ni][j] + bb2;
    }
  }
}

// ---------------------------------------------------------------------------
// Fallback GEMM (round-2 proven): B is f32 [K][N], converted during staging.
// ---------------------------------------------------------------------------
template <int EPI>
__global__ __launch_bounds__(256)
void gemm_bf16(const unsigned short* __restrict__ A,
               const float* __restrict__ B,
               const float* __restrict__ bias,
               unsigned short* __restrict__ Cb,
               float* __restrict__ Cf,
               int K, int N) {
  __shared__ __align__(16) unsigned short As[128 * 64];
  __shared__ __align__(16) unsigned short Bs[128 * 64];

  const int tid = threadIdx.x;
  const int lane = tid & 63;
  const int wv = tid >> 6;
  const int wm = wv >> 1, wn = wv & 1;
  const int mt = blockIdx.x & 31;
  const int nt = blockIdx.x >> 5;
  const int m0 = mt * 128, n0 = nt * 128;

  f32x4 acc[4][4] = {};

  for (int kt = 0; kt < K; kt += 64) {
    __syncthreads();
#pragma unroll
    for (int i = 0; i < 4; ++i) {
      int q = tid + 256 * i;
      int row = q >> 3;
      int kc = q & 7;
      uint4v v = *(const uint4v*)((const char*)A +
                   ((size_t)(m0 + row) * K + kt) * 2 + kc * 16);
      *(uint4v*)((char*)As + row * 128 + ((kc * 16) ^ ((row & 7) << 4))) = v;
    }
#pragma unroll
    for (int gi = 0; gi < 4; ++gi) {
      int q = tid + 256 * gi;
      int nn = q & 127;
      int k8 = q >> 7;
      const float* src = B + (size_t)(kt + k8 * 8) * N + (n0 + nn);
      ushort8 tv;
#pragma unroll
      for (int j = 0; j < 8; ++j) tv[j] = f2bf(src[(size_t)j * N]);
      *(ushort8*)((char*)Bs + nn * 128 + ((k8 * 16) ^ ((nn & 7) << 4))) = tv;
    }
    __syncthreads();
#pragma unroll
    for (int kk = 0; kk < 2; ++kk) {
      short8 av[4], bv[4];
      const int kb = kk * 64 + (lane >> 4) * 16;
#pragma unroll
      for (int mi = 0; mi < 4; ++mi) {
        int row = wm * 64 + mi * 16 + (lane & 15);
        av[mi] = *(const short8*)((const char*)As + row * 128 + (kb ^ ((row & 7) << 4)));
      }
#pragma unroll
      for (int ni = 0; ni < 4; ++ni) {
        int row = wn * 64 + ni * 16 + (lane & 15);
        bv[ni] = *(const short8*)((const char*)Bs + row * 128 + (kb ^ ((row & 7) << 4)));
      }
#pragma unroll
      for (int mi = 0; mi < 4; ++mi)
#pragma unroll
        for (int ni = 0; ni < 4; ++ni)
          acc[mi][ni] = __builtin_amdgcn_mfma_f32_16x16x32_bf16(av[mi], bv[ni], acc[mi][ni], 0, 0, 0);
    }
  }

  const int lr = lane >> 4, lc = lane & 15;
#pragma unroll
  for (int ni = 0; ni < 4; ++ni) {
    int c = n0 + wn * 64 + ni * 16 + lc;
    float bb = bias[c];
#pragma unroll
    for (int mi = 0; mi < 4; ++mi) {
      int r0 = m0 + wm * 64 + mi * 16 + lr * 4;
      f32x4 v = acc[mi][ni];
#pragma unroll
      for (int j = 0; j < 4; ++j) {
        float val = v[j] + bb;
        size_t idx = (size_t)(r0 + j) * N + c;
        if (EPI == 1) { Cb[idx] = f2bf(tanhf(val)); }
        else { Cf[idx] = val; }
      }
    }
  }
}

// ---------------------------------------------------------------------------
extern "C" void kernel_launch(void* const* d_in, const int* in_sizes, int n_in,
                              void* d_out, int out_size, void* d_ws, size_t ws_size,
                              hipStream_t stream) {
  const float* x     = (const float*)d_in[0];  // [4,1024,3072]
  const float* w     = (const float*)d_in[1];  // [3,3072]
  const float* emb_w = (const float*)d_in[2];  // [3072,2048]
  const float* emb_b = (const float*)d_in[3];  // [3,2048]
  const float* lin_w = (const float*)d_in[4];  // [2,2048,2048]
  const float* lin_b = (const float*)d_in[5];  // [2,2048]
  const float* out_w = (const float*)d_in[6];  // [2048,32000]
  const float* out_b = (const float*)d_in[7];  // [32000]
  float* out = (float*)d_out;                  // [4096,32000] f32

  char* ob = (char*)d_out;
  unsigned short* xg      = (unsigned short*)ob;
  unsigned short* h0      = (unsigned short*)(ob + (((size_t)128) << 20));
  unsigned short* h1      = (unsigned short*)(ob + (((size_t)160) << 20));
  unsigned short* emb_wT  = (unsigned short*)(ob + (((size_t)192) << 20));
  unsigned short* lin_wT0 = (unsigned short*)(ob + (((size_t)208) << 20));
  unsigned short* lin_wT1 = (unsigned short*)(ob + (((size_t)224) << 20));
  unsigned short* h2      = (unsigned short*)d_ws;
  unsigned short* out_wT  = (unsigned short*)((char*)d_ws + (((size_t)32) << 20));
  const bool fast4 = ws_size >= ((((size_t)32) << 20) + (size_t)32000 * 2048 * 2);

  gates_kernel<<<4096, 256, 0, stream>>>(x, w, xg);
  transcvt_kernel<<<dim3(32, 48), 256, 0, stream>>>(emb_w, emb_wT, 3072, 2048);
  transcvt_kernel<<<dim3(32, 32), 256, 0, stream>>>(lin_w, lin_wT0, 2048, 2048);
  transcvt_kernel<<<dim3(32, 32), 256, 0, stream>>>(lin_w + 2048 * 2048, lin_wT1, 2048, 2048);
  if (fast4)
    transcvt_kernel<<<dim3(500, 32), 256, 0, stream>>>(out_w, out_wT, 2048, 32000);

  gemm_tt<0><<<32 * 16, 256, 0, stream>>>(xg, emb_wT, emb_b, h0, nullptr, 3072, 2048);
  gemm_tt<1><<<32 * 16, 256, 0, stream>>>(h0, lin_wT0, lin_b, h1, nullptr, 2048, 2048);
  gemm_tt<1><<<32 * 16, 256, 0, stream>>>(h1, lin_wT1, lin_b + 2048, h2, nullptr, 2048, 2048);
  if (fast4)
    gemm8_out<<<16 * 125, 512, 0, stream>>>(h2, out_wT, out_b, out, 2048, 32000);
  else
    gemm_bf16<2><<<32 * 250, 256, 0, stream>>>(h2, out_w, out_b, nullptr, out, 2048, 32000);
}